// Round 14
// baseline (248.436 us; speedup 1.0000x reference)
//
#include <hip/hip_runtime.h>
#include <hip/hip_bf16.h>

typedef __hip_bfloat16 bf16;
typedef __bf16 bf16x8 __attribute__((ext_vector_type(8)));
typedef float f32x4 __attribute__((ext_vector_type(4)));
typedef float f32x16 __attribute__((ext_vector_type(16)));

#define DEV __device__ __forceinline__

DEV int swz(int r, int k) { return r * 64 + (k ^ ((r & 7) << 3)); }

#define GLOAD_LDS16(gaddr, laddr)                                              \
  __builtin_amdgcn_global_load_lds(                                            \
      (const __attribute__((address_space(1))) void*)(gaddr),                  \
      (__attribute__((address_space(3))) void*)(laddr), 16, 0, 0)

// ------ prep: QKV/O weight transposes + bias concat + LN1 ------
__global__ void prep_kernel(
    const float* __restrict__ Wq, const float* __restrict__ Wk,
    const float* __restrict__ Wv, const float* __restrict__ Wo,
    const float* __restrict__ bq, const float* __restrict__ bk,
    const float* __restrict__ bv,
    bf16* __restrict__ WqkvT, bf16* __restrict__ WoT, float* __restrict__ bqkv,
    const float* __restrict__ in, const float* __restrict__ g1,
    const float* __restrict__ b1v, float* __restrict__ xo, bf16* __restrict__ xb) {
  __shared__ bf16 t[32][33];
  __shared__ float ss[4], qq[4];
  int bid = blockIdx.x;
  if (bid >= 4108) {  // LN1 rows
    int row = bid - 4108, tid = threadIdx.y * 32 + threadIdx.x;
    int lane = tid & 63, w = tid >> 6;
    float4 v = reinterpret_cast<const float4*>(in + (size_t)row * 1024)[tid];
    float s = v.x + v.y + v.z + v.w;
    float sq = v.x * v.x + v.y * v.y + v.z * v.z + v.w * v.w;
#pragma unroll
    for (int m = 32; m; m >>= 1) { s += __shfl_xor(s, m); sq += __shfl_xor(sq, m); }
    if (lane == 0) { ss[w] = s; qq[w] = sq; }
    __syncthreads();
    s = ss[0] + ss[1] + ss[2] + ss[3];
    sq = qq[0] + qq[1] + qq[2] + qq[3];
    float mu = s * (1.f / 1024.f);
    float rs = rsqrtf(sq * (1.f / 1024.f) - mu * mu + 1e-5f);
    float4 gg = reinterpret_cast<const float4*>(g1)[tid];
    float4 bb = reinterpret_cast<const float4*>(b1v)[tid];
    float4 y;
    y.x = (v.x - mu) * rs * gg.x + bb.x;
    y.y = (v.y - mu) * rs * gg.y + bb.y;
    y.z = (v.z - mu) * rs * gg.z + bb.z;
    y.w = (v.w - mu) * rs * gg.w + bb.w;
    reinterpret_cast<float4*>(xo + (size_t)row * 1024)[tid] = y;
    union { bf16 h[4]; uint2 u; } pk;
    pk.h[0] = __float2bfloat16(y.x); pk.h[1] = __float2bfloat16(y.y);
    pk.h[2] = __float2bfloat16(y.z); pk.h[3] = __float2bfloat16(y.w);
    reinterpret_cast<uint2*>(xb + (size_t)row * 1024)[tid] = pk.u;
    return;
  }
  if (bid >= 4096) {  // bias concat
    int i = (bid - 4096) * 256 + threadIdx.y * 32 + threadIdx.x;
    if (i < 3072)
      bqkv[i] = i < 1024 ? bq[i] : (i < 2048 ? bk[i - 1024] : bv[i - 2048]);
    return;
  }
  int wsel = bid >> 10;
  const float* src = wsel == 0 ? Wq : wsel == 1 ? Wk : wsel == 2 ? Wv : Wo;
  bf16* dst = wsel < 3 ? WqkvT + (size_t)wsel * 1048576 : WoT;
  int tb = bid & 1023;
  int bx = (tb & 31) * 32, by = (tb >> 5) * 32;
  int tx = threadIdx.x, ty = threadIdx.y;
#pragma unroll
  for (int j = 0; j < 32; j += 8)
    t[ty + j][tx] = __float2bfloat16(src[(size_t)(by + ty + j) * 1024 + bx + tx]);
  __syncthreads();
#pragma unroll
  for (int j = 0; j < 32; j += 8)
    dst[(size_t)(bx + ty + j) * 1024 + by + tx] = t[tx][ty + j];
}

// ------- LN23 -------
__global__ __launch_bounds__(256) void ln23_kernel(
    const float* __restrict__ x, const float* __restrict__ ao,
    const float* __restrict__ g2, const float* __restrict__ b2,
    const float* __restrict__ g3, const float* __restrict__ b3,
    float* __restrict__ x2o, bf16* __restrict__ hb) {
  int row = blockIdx.x, tid = threadIdx.x;
  int lane = tid & 63, w = tid >> 6;
  float4 a = reinterpret_cast<const float4*>(ao + (size_t)row * 1024)[tid];
  float s = a.x + a.y + a.z + a.w;
  float sq = a.x * a.x + a.y * a.y + a.z * a.z + a.w * a.w;
#pragma unroll
  for (int m = 32; m; m >>= 1) { s += __shfl_xor(s, m); sq += __shfl_xor(sq, m); }
  __shared__ float s1[4], q1[4], s2[4], q2[4];
  if (lane == 0) { s1[w] = s; q1[w] = sq; }
  __syncthreads();
  s = s1[0] + s1[1] + s1[2] + s1[3];
  sq = q1[0] + q1[1] + q1[2] + q1[3];
  float mu = s * (1.f / 1024.f);
  float rs = rsqrtf(sq * (1.f / 1024.f) - mu * mu + 1e-5f);
  float4 xr = reinterpret_cast<const float4*>(x + (size_t)row * 1024)[tid];
  float4 gg = reinterpret_cast<const float4*>(g2)[tid];
  float4 bb = reinterpret_cast<const float4*>(b2)[tid];
  float4 x2;
  x2.x = xr.x + (a.x - mu) * rs * gg.x + bb.x;
  x2.y = xr.y + (a.y - mu) * rs * gg.y + bb.y;
  x2.z = xr.z + (a.z - mu) * rs * gg.z + bb.z;
  x2.w = xr.w + (a.w - mu) * rs * gg.w + bb.w;
  reinterpret_cast<float4*>(x2o + (size_t)row * 1024)[tid] = x2;
  s = x2.x + x2.y + x2.z + x2.w;
  sq = x2.x * x2.x + x2.y * x2.y + x2.z * x2.z + x2.w * x2.w;
#pragma unroll
  for (int m = 32; m; m >>= 1) { s += __shfl_xor(s, m); sq += __shfl_xor(sq, m); }
  if (lane == 0) { s2[w] = s; q2[w] = sq; }
  __syncthreads();
  s = s2[0] + s2[1] + s2[2] + s2[3];
  sq = q2[0] + q2[1] + q2[2] + q2[3];
  mu = s * (1.f / 1024.f);
  rs = rsqrtf(sq * (1.f / 1024.f) - mu * mu + 1e-5f);
  gg = reinterpret_cast<const float4*>(g3)[tid];
  bb = reinterpret_cast<const float4*>(b3)[tid];
  union { bf16 h[4]; uint2 u; } pk;
  pk.h[0] = __float2bfloat16((x2.x - mu) * rs * gg.x + bb.x);
  pk.h[1] = __float2bfloat16((x2.y - mu) * rs * gg.y + bb.y);
  pk.h[2] = __float2bfloat16((x2.z - mu) * rs * gg.z + bb.z);
  pk.h[3] = __float2bfloat16((x2.w - mu) * rs * gg.w + bb.w);
  reinterpret_cast<uint2*>(hb + (size_t)row * 1024)[tid] = pk.u;
}

// ===== GEMM, 2-phase dbuf, 32x32x16 MFMA (half the MFMA issue count) =====
// A/B frag: row=lane&31, k=(lane>>5)*8+j. C/D: col=lane&31,
// row=(q&3)+8*(q>>2)+4*(lane>>5) (m74/m101-verified mapping).
// Staging is wave-strided over 1KB chunks (supports any wave count).
template <int BM, int BN, int WM, int WN, int MINW,
          bool GELU, bool RES, bool OUTBF, bool VSPLIT>
__global__ __launch_bounds__(WM * WN * 64, MINW) void gemm32(
    const bf16* __restrict__ A, const bf16* __restrict__ BT,
    const float* __restrict__ bias, const float* __restrict__ res,
    float* __restrict__ outf, bf16* __restrict__ outb,
    bf16* __restrict__ kt, bf16* __restrict__ vt,
    int M, int N, int K) {
  constexpr int NW = WM * WN;
  constexpr int MT = BM / WM / 32, NT = BN / WN / 32;
  constexpr int ACH = BM / 8, BCH = BN / 8, TOT = ACH + BCH;
  __shared__ __align__(16) bf16 As[2][BM * 64];
  __shared__ __align__(16) bf16 Bs[2][BN * 64];
  const int t = threadIdx.x, lane = t & 63, w = t >> 6;
  const int wr = w / WN, wc = w % WN;
  const int l31 = lane & 31, l5 = lane >> 5;
  const int gx = gridDim.x, nwg = gx * gridDim.y;
  int bid = blockIdx.y * gx + blockIdx.x;
  int sbid = (bid & 7) * (nwg >> 3) + (bid >> 3);
  const int m0 = (sbid / gx) * BM, n0 = (sbid % gx) * BN;
  const int lr = lane >> 3;
  const int scol = ((lane & 7) * 8) ^ (lr * 8);

  auto stage = [&](int buf, int kt_) {
    const int k0 = kt_ << 6;
    for (int c = w; c < TOT; c += NW) {
      if (c < ACH) {
        GLOAD_LDS16(A + (size_t)(m0 + c * 8 + lr) * K + k0 + scol, &As[buf][c * 512]);
      } else {
        int c2 = c - ACH;
        GLOAD_LDS16(BT + (size_t)(n0 + c2 * 8 + lr) * K + k0 + scol, &Bs[buf][c2 * 512]);
      }
    }
  };

  f32x16 acc[MT][NT] = {};
  const int nk = K >> 6;
  stage(0, 0);
  __syncthreads();
  int cur = 0;
  for (int kk = 0; kk < nk; ++kk) {
    if (kk + 1 < nk) stage(cur ^ 1, kk + 1);
#pragma unroll
    for (int ks = 0; ks < 4; ++ks) {
      const int kb = ks * 16 + l5 * 8;
      bf16x8 af[MT], bfr[NT];
#pragma unroll
      for (int m = 0; m < MT; ++m)
        af[m] = *reinterpret_cast<const bf16x8*>(
            &As[cur][swz(wr * (BM / WM) + m * 32 + l31, kb)]);
#pragma unroll
      for (int n = 0; n < NT; ++n)
        bfr[n] = *reinterpret_cast<const bf16x8*>(
            &Bs[cur][swz(wc * (BN / WN) + n * 32 + l31, kb)]);
      __builtin_amdgcn_s_setprio(1);
#pragma unroll
      for (int m = 0; m < MT; ++m)
#pragma unroll
        for (int n = 0; n < NT; ++n)
          acc[m][n] = __builtin_amdgcn_mfma_f32_32x32x16_bf16(af[m], bfr[n], acc[m][n], 0, 0, 0);
      __builtin_amdgcn_s_setprio(0);
    }
    __syncthreads();
    cur ^= 1;
  }

#pragma unroll
  for (int m = 0; m < MT; ++m) {
    int grb = m0 + wr * (BM / WM) + m * 32 + 4 * l5;
#pragma unroll
    for (int n = 0; n < NT; ++n) {
      int gc = n0 + wc * (BN / WN) + n * 32 + l31;
      float bv = bias[gc];
#pragma unroll
      for (int q = 0; q < 16; ++q) {
        int gr = grb + (q & 3) + 8 * (q >> 2);
        float v = acc[m][n][q] + bv;
        if constexpr (GELU) v = 0.5f * v * (1.f + erff(v * 0.70710678118654752f));
        if constexpr (RES) v += res[(size_t)gr * N + gc];
        if constexpr (VSPLIT) {
          int s = gr & 1023, bb = gr >> 10;
          if (gc < 1024) {
            outb[(size_t)gr * N + gc] = __float2bfloat16(v);
          } else if (gc < 2048) {
            int hd = gc - 1024, hh = hd >> 6, d = hd & 63;
            int ln = (s & 15) | (((d >> 3) & 3) << 4);
            kt[(((size_t)(bb * 16 + hh) * 64 + (s >> 4)) << 10) + (d >> 5) * 512 +
               ln * 8 + (d & 7)] = __float2bfloat16(v);
          } else {
            int hd = gc - 2048, hh = hd >> 6, d = hd & 63;
            int ln = (d & 15) | (((s >> 3) & 3) << 4);
            vt[(((size_t)(bb * 16 + hh) * 4 + (d >> 4)) << 14) + ((s >> 5) << 9) +
               ln * 8 + (s & 7)] = __float2bfloat16(v);
          }
        } else if constexpr (OUTBF) {
          outb[(size_t)gr * N + gc] = __float2bfloat16(v);
        } else {
          outf[(size_t)gr * N + gc] = v;
        }
      }
    }
  }
}

// -------- flash attention (fragment-linear K/V, uniform-work pairs) --------
// Blocks >= 512 piggyback the W1/W2 transposes (consumed 2+ dispatches later).
__global__ __launch_bounds__(256, 2) void attn_kernel(
    const bf16* __restrict__ qkv, const bf16* __restrict__ kt,
    const bf16* __restrict__ vt, bf16* __restrict__ o,
    const float* __restrict__ W1, const float* __restrict__ W2,
    bf16* __restrict__ W1T, bf16* __restrict__ W2T) {
  const int S = 1024, QS = 3072, HD = 1024;
  constexpr int PSTR = 72;
  __shared__ __align__(16) bf16 P[4][16 * PSTR];
  __shared__ bf16 tt[32][33];
  int bid = blockIdx.x;
  const int t = threadIdx.x, lane = t & 63, w = t >> 6;
  if (bid >= 512) {  // W1 / W2 transpose tail
    int b2 = bid - 512;
    const float* src; bf16* dst; int K, N, tb;
    if (b2 < 4096) { src = W1; dst = W1T; K = 1024; N = 4096; tb = b2; }
    else           { src = W2; dst = W2T; K = 4096; N = 1024; tb = b2 - 4096; }
    int ntx = N >> 5;
    int bx = (tb % ntx) * 32, by = (tb / ntx) * 32;
    int tx = t & 31, ty = t >> 5;
#pragma unroll
    for (int j = 0; j < 32; j += 8)
      tt[ty + j][tx] = __float2bfloat16(src[(size_t)(by + ty + j) * N + bx + tx]);
    __syncthreads();
#pragma unroll
    for (int j = 0; j < 32; j += 8)
      dst[(size_t)(bx + ty + j) * K + by + tx] = tt[tx][ty + j];
    return;
  }
  int xcd = bid & 7, j = bid >> 3;
  int grp = xcd * 8 + (j >> 3);
  int pr = j & 7;
  const int b = grp >> 4, h = grp & 15;
  const int l15 = lane & 15, l4 = lane >> 4;

  const bf16* qg = qkv;
  const int bh = b * 16 + h;
  const bf16* kbase = kt + ((size_t)bh << 16) + lane * 8;
  const bf16* vbase = vt + ((size_t)bh << 16) + lane * 8;

  bf16x8 kA[8], kB[8];
  auto loadK = [&](int kb, bf16x8* kf) {
#pragma unroll
    for (int cb = 0; cb < 4; ++cb)
#pragma unroll
      for (int ks = 0; ks < 2; ++ks)
        kf[cb * 2 + ks] = *reinterpret_cast<const bf16x8*>(
            kbase + (((kb >> 4) + cb) << 10) + (ks << 9));
  };

  auto run_strip = [&](int q0) {
    bf16x8 qf0, qf1;
    {
      const bf16* qp = qg + (size_t)(b * S + q0 + l15) * QS + h * 64 + l4 * 8;
      qf0 = *reinterpret_cast<const bf16x8*>(qp);
      qf1 = *reinterpret_cast<const bf16x8*>(qp + 32);
    }
    f32x4 acc[4] = {};
    float mrow = -1e30f, lrow = 0.f;
    const int kmaxa = q0 + 15, kmax = kmaxa < 959 ? kmaxa : 959;
    const int nt = (kmax >> 6) + 1;
    loadK(0, kA);

    for (int kt_ = 0; kt_ < nt; ++kt_) {
      const int kb = kt_ << 6;
      bf16x8* kf = (kt_ & 1) ? kB : kA;
      bf16x8* kn = (kt_ & 1) ? kA : kB;
      bf16x8 vf[8];
#pragma unroll
      for (int n = 0; n < 4; ++n)
#pragma unroll
        for (int ks = 0; ks < 2; ++ks)
          vf[n * 2 + ks] = *reinterpret_cast<const bf16x8*>(
              vbase + (n << 14) + (((kb >> 5) + ks) << 9));
      if (kt_ + 1 < nt) loadK(kb + 64, kn);

      f32x4 sc[4];
      __builtin_amdgcn_s_setprio(1);
#pragma unroll
      for (int cb = 0; cb < 4; ++cb) {
        f32x4 z = {};
        z = __builtin_amdgcn_mfma_f32_16x16x32_bf16(kf[cb * 2 + 0], qf0, z, 0, 0, 0);
        z = __builtin_amdgcn_mfma_f32_16x16x32_bf16(kf[cb * 2 + 1], qf1, z, 0, 0, 0);
        sc[cb] = z;
      }
      __builtin_amdgcn_s_setprio(0);

      const int q = q0 + l15;
      float p[16];
#pragma unroll
      for (int cb = 0; cb < 4; ++cb)
#pragma unroll
        for (int r = 0; r < 4; ++r) {
          int kgl = kb + cb * 16 + l4 * 4 + r;
          p[cb * 4 + r] = (kgl > q) ? -1e30f : sc[cb][r] * 0.125f;
        }
      float tm = p[0];
#pragma unroll
      for (int i = 1; i < 16; ++i) tm = fmaxf(tm, p[i]);
      tm = fmaxf(tm, __shfl_xor(tm, 16));
      tm = fmaxf(tm, __shfl_xor(tm, 32));
      bool defer = __all(tm <= mrow + 8.f);   // T13
      float mn = defer ? mrow : fmaxf(mrow, tm);
      float ps = 0.f;
#pragma unroll
      for (int i = 0; i < 16; ++i) { p[i] = __expf(p[i] - mn); ps += p[i]; }
      ps += __shfl_xor(ps, 16);
      ps += __shfl_xor(ps, 32);
      if (defer) {
        lrow += ps;
      } else {
        float al = __expf(mrow - mn);
        mrow = mn;
        lrow = lrow * al + ps;
#pragma unroll
        for (int n = 0; n < 4; ++n)
#pragma unroll
          for (int r = 0; r < 4; ++r) acc[n][r] *= al;
      }
#pragma unroll
      for (int cb = 0; cb < 4; ++cb) {
        union { bf16 h4[4]; uint2 u; } pk;
#pragma unroll
        for (int r = 0; r < 4; ++r) pk.h4[r] = __float2bfloat16(p[cb * 4 + r]);
        *reinterpret_cast<uint2*>(&P[w][l15 * PSTR + cb * 16 + l4 * 4]) = pk.u;
      }
      asm volatile("" ::: "memory");
      bf16x8 pb0 = *reinterpret_cast<const bf16x8*>(&P[w][l15 * PSTR + l4 * 8]);
      bf16x8 pb1 = *reinterpret_cast<const bf16x8*>(&P[w][l15 * PSTR + 32 + l4 * 8]);
      __builtin_amdgcn_s_setprio(1);
#pragma unroll
      for (int n = 0; n < 4; ++n) {
        acc[n] = __builtin_amdgcn_mfma_f32_16x16x32_bf16(vf[n * 2 + 0], pb0, acc[n], 0, 0, 0);
        acc[n] = __builtin_amdgcn_mfma_f32_16x16x32_bf16(vf[n * 2 + 1], pb1, acc[n], 0, 0, 0);
      }
      __builtin_amdgcn_s_setprio(0);
    }

    float inv = 1.f / lrow;
#pragma unroll
    for (int n = 0; n < 4; ++n) {
      union { bf16 h4[4]; uint2 u; } pk;
#pragma unroll
      for (int r = 0; r < 4; ++r) pk.h4[r] = __float2bfloat16(acc[n][r] * inv);
      *reinterpret_cast<uint2*>(&P[w][l15 * PSTR + n * 16 + l4 * 4]) = pk.u;
    }
    asm volatile("" ::: "memory");
    {
      int qq = lane >> 2, c = lane & 3;
#pragma unroll
      for (int i = 0; i < 2; ++i) {
        uint4 ov = *reinterpret_cast<const uint4*>(&P[w][qq * PSTR + c * 16 + i * 8]);
        *reinterpret_cast<uint4*>(
            o + (size_t)(b * S + q0 + qq) * HD + h * 64 + c * 16 + i * 8) = ov;
      }
    }
    asm volatile("" ::: "memory");
  };

  run_strip(pr * 64 + w * 16);
  run_strip((15 - pr) * 64 + w * 16);
}

// ---------------- launch ----------------
extern "C" void kernel_launch(void* const* d_in, const int* in_sizes, int n_in,
                              void* d_out, int out_size, void* d_ws, size_t ws_size,
                              hipStream_t stream) {
  const float* input = (const float*)d_in[0];
  const float* ln1g = (const float*)d_in[3];
  const float* ln1b = (const float*)d_in[4];
  const float* ln2g = (const float*)d_in[5];
  const float* ln2b = (const float*)d_in[6];
  const float* ln3g = (const float*)d_in[7];
  const float* ln3b = (const float*)d_in[8];
  const float* Wq = (const float*)d_in[9];  const float* bq = (const float*)d_in[10];
  const float* Wk = (const float*)d_in[11]; const float* bk = (const float*)d_in[12];
  const float* Wv = (const float*)d_in[13]; const float* bv = (const float*)d_in[14];
  const float* Wo = (const float*)d_in[15]; const float* bo = (const float*)d_in[16];
  const float* W1 = (const float*)d_in[17]; const float* b1 = (const float*)d_in[18];
  const float* W2 = (const float*)d_in[19]; const float* b2 = (const float*)d_in[20];

  const int M = 4096, D = 1024, F = 4096;
  char* p = (char*)d_ws;
  size_t off = 0;
  auto nxt = [&](size_t n) { char* r = p + off; off += n; return r; };
  bf16* WqkvT = (bf16*)nxt((size_t)3 * D * D * 2);
  bf16* WoT = (bf16*)nxt((size_t)D * D * 2);
  bf16* W1T = (bf16*)nxt((size_t)F * D * 2);
  bf16* W2T = (bf16*)nxt((size_t)D * F * 2);
  float* bqkv = (float*)nxt(16384);
  float* xf  = (float*)nxt((size_t)M * D * 4);
  float* aof = (float*)nxt((size_t)M * D * 4);
  float* x2f = (float*)nxt((size_t)M * D * 4);
  bf16* xb = (bf16*)nxt((size_t)M * D * 2);
  bf16* qkv = (bf16*)nxt((size_t)M * 3 * D * 2);
  bf16* ktb = (bf16*)aof;                       // K packed, 8 MB (aof dead until Wo)
  bf16* vtb = (bf16*)((char*)aof + (size_t)8 * 1024 * 1024);  // V^T packed, 8 MB
  bf16* gb = (bf16*)xf;   // gelu out overlays xf+aof (both dead by then)
  bf16* ab = xb;
  bf16* hb = qkv;

  // prep: QKV/O transposes + bias concat + LN1
  prep_kernel<<<4108 + 4096, dim3(32, 8), 0, stream>>>(
      Wq, Wk, Wv, Wo, bq, bk, bv, WqkvT, WoT, bqkv,
      input, ln1g, ln1b, xf, xb);

  // fused QKV: [4096,3072], 256x192 tile, 6 waves, 256 blocks (full CU cover)
  gemm32<256, 192, 2, 3, 1, false, false, true, true>
      <<<dim3(16, 16), 384, 0, stream>>>(
      xb, WqkvT, bqkv, nullptr, nullptr, qkv, ktb, vtb, M, 3 * D, D);

  // attention (512 blocks) + piggybacked W1/W2 transposes (8192 blocks)
  attn_kernel<<<512 + 8192, 256, 0, stream>>>(qkv, ktb, vtb, ab, W1, W2, W1T, W2T);

  gemm32<128, 64, 2, 2, 4, false, false, false, false>
      <<<dim3(16, 32), 256, 0, stream>>>(
      ab, WoT, bo, nullptr, aof, nullptr, nullptr, nullptr, M, D, D);

  ln23_kernel<<<M, 256, 0, stream>>>(xf, aof, ln2g, ln2b, ln3g, ln3b, x2f, hb);

  // W1+GELU: [4096,4096], 256^2 tile, 8 waves
  gemm32<256, 256, 2, 4, 1, true, false, true, false>
      <<<dim3(16, 16), 512, 0, stream>>>(
      hb, W1T, b1, nullptr, nullptr, gb, nullptr, nullptr, M, F, D);
  // W2+residual: [4096,1024], K=4096, 128x64 tile
  gemm32<128, 64, 2, 2, 4, false, true, false, false>
      <<<dim3(16, 32), 256, 0, stream>>>(
      gb, W2T, b2, x2f, (float*)d_out, nullptr, nullptr, nullptr, M, D, F);
}

// Round 15
// 217.476 us; speedup vs baseline: 1.1424x; 1.1424x over previous
//
#include <hip/hip_runtime.h>
#include <hip/hip_bf16.h>

typedef __hip_bfloat16 bf16;
typedef __bf16 bf16x8 __attribute__((ext_vector_type(8)));
typedef float f32x4 __attribute__((ext_vector_type(4)));

#define DEV __device__ __forceinline__

DEV int swz(int r, int k) { return r * 64 + (k ^ ((r & 7) << 3)); }

#define GLOAD_LDS16(gaddr, laddr)                                              \
  __builtin_amdgcn_global_load_lds(                                            \
      (const __attribute__((address_space(1))) void*)(gaddr),                  \
      (__attribute__((address_space(3))) void*)(laddr), 16, 0, 0)

// ------ prep: QKV/O weight transposes + bias concat + LN1 ------
__global__ void prep_kernel(
    const float* __restrict__ Wq, const float* __restrict__ Wk,
    const float* __restrict__ Wv, const float* __restrict__ Wo,
    const float* __restrict__ bq, const float* __restrict__ bk,
    const float* __restrict__ bv,
    bf16* __restrict__ WqkvT, bf16* __restrict__ WoT, float* __restrict__ bqkv,
    const float* __restrict__ in, const float* __restrict__ g1,
    const float* __restrict__ b1v, float* __restrict__ xo, bf16* __restrict__ xb) {
  __shared__ bf16 t[32][33];
  __shared__ float ss[4], qq[4];
  int bid = blockIdx.x;
  if (bid >= 4108) {  // LN1 rows
    int row = bid - 4108, tid = threadIdx.y * 32 + threadIdx.x;
    int lane = tid & 63, w = tid >> 6;
    float4 v = reinterpret_cast<const float4*>(in + (size_t)row * 1024)[tid];
    float s = v.x + v.y + v.z + v.w;
    float sq = v.x * v.x + v.y * v.y + v.z * v.z + v.w * v.w;
#pragma unroll
    for (int m = 32; m; m >>= 1) { s += __shfl_xor(s, m); sq += __shfl_xor(sq, m); }
    if (lane == 0) { ss[w] = s; qq[w] = sq; }
    __syncthreads();
    s = ss[0] + ss[1] + ss[2] + ss[3];
    sq = qq[0] + qq[1] + qq[2] + qq[3];
    float mu = s * (1.f / 1024.f);
    float rs = rsqrtf(sq * (1.f / 1024.f) - mu * mu + 1e-5f);
    float4 gg = reinterpret_cast<const float4*>(g1)[tid];
    float4 bb = reinterpret_cast<const float4*>(b1v)[tid];
    float4 y;
    y.x = (v.x - mu) * rs * gg.x + bb.x;
    y.y = (v.y - mu) * rs * gg.y + bb.y;
    y.z = (v.z - mu) * rs * gg.z + bb.z;
    y.w = (v.w - mu) * rs * gg.w + bb.w;
    reinterpret_cast<float4*>(xo + (size_t)row * 1024)[tid] = y;
    union { bf16 h[4]; uint2 u; } pk;
    pk.h[0] = __float2bfloat16(y.x); pk.h[1] = __float2bfloat16(y.y);
    pk.h[2] = __float2bfloat16(y.z); pk.h[3] = __float2bfloat16(y.w);
    reinterpret_cast<uint2*>(xb + (size_t)row * 1024)[tid] = pk.u;
    return;
  }
  if (bid >= 4096) {  // bias concat
    int i = (bid - 4096) * 256 + threadIdx.y * 32 + threadIdx.x;
    if (i < 3072)
      bqkv[i] = i < 1024 ? bq[i] : (i < 2048 ? bk[i - 1024] : bv[i - 2048]);
    return;
  }
  int wsel = bid >> 10;
  const float* src = wsel == 0 ? Wq : wsel == 1 ? Wk : wsel == 2 ? Wv : Wo;
  bf16* dst = wsel < 3 ? WqkvT + (size_t)wsel * 1048576 : WoT;
  int tb = bid & 1023;
  int bx = (tb & 31) * 32, by = (tb >> 5) * 32;
  int tx = threadIdx.x, ty = threadIdx.y;
#pragma unroll
  for (int j = 0; j < 32; j += 8)
    t[ty + j][tx] = __float2bfloat16(src[(size_t)(by + ty + j) * 1024 + bx + tx]);
  __syncthreads();
#pragma unroll
  for (int j = 0; j < 32; j += 8)
    dst[(size_t)(bx + ty + j) * 1024 + by + tx] = t[tx][ty + j];
}

// ------- LN23 -------
__global__ __launch_bounds__(256) void ln23_kernel(
    const float* __restrict__ x, const float* __restrict__ ao,
    const float* __restrict__ g2, const float* __restrict__ b2,
    const float* __restrict__ g3, const float* __restrict__ b3,
    float* __restrict__ x2o, bf16* __restrict__ hb) {
  int row = blockIdx.x, tid = threadIdx.x;
  int lane = tid & 63, w = tid >> 6;
  float4 a = reinterpret_cast<const float4*>(ao + (size_t)row * 1024)[tid];
  float s = a.x + a.y + a.z + a.w;
  float sq = a.x * a.x + a.y * a.y + a.z * a.z + a.w * a.w;
#pragma unroll
  for (int m = 32; m; m >>= 1) { s += __shfl_xor(s, m); sq += __shfl_xor(sq, m); }
  __shared__ float s1[4], q1[4], s2[4], q2[4];
  if (lane == 0) { s1[w] = s; q1[w] = sq; }
  __syncthreads();
  s = s1[0] + s1[1] + s1[2] + s1[3];
  sq = q1[0] + q1[1] + q1[2] + q1[3];
  float mu = s * (1.f / 1024.f);
  float rs = rsqrtf(sq * (1.f / 1024.f) - mu * mu + 1e-5f);
  float4 xr = reinterpret_cast<const float4*>(x + (size_t)row * 1024)[tid];
  float4 gg = reinterpret_cast<const float4*>(g2)[tid];
  float4 bb = reinterpret_cast<const float4*>(b2)[tid];
  float4 x2;
  x2.x = xr.x + (a.x - mu) * rs * gg.x + bb.x;
  x2.y = xr.y + (a.y - mu) * rs * gg.y + bb.y;
  x2.z = xr.z + (a.z - mu) * rs * gg.z + bb.z;
  x2.w = xr.w + (a.w - mu) * rs * gg.w + bb.w;
  reinterpret_cast<float4*>(x2o + (size_t)row * 1024)[tid] = x2;
  s = x2.x + x2.y + x2.z + x2.w;
  sq = x2.x * x2.x + x2.y * x2.y + x2.z * x2.z + x2.w * x2.w;
#pragma unroll
  for (int m = 32; m; m >>= 1) { s += __shfl_xor(s, m); sq += __shfl_xor(sq, m); }
  if (lane == 0) { s2[w] = s; q2[w] = sq; }
  __syncthreads();
  s = s2[0] + s2[1] + s2[2] + s2[3];
  sq = q2[0] + q2[1] + q2[2] + q2[3];
  mu = s * (1.f / 1024.f);
  rs = rsqrtf(sq * (1.f / 1024.f) - mu * mu + 1e-5f);
  gg = reinterpret_cast<const float4*>(g3)[tid];
  bb = reinterpret_cast<const float4*>(b3)[tid];
  union { bf16 h[4]; uint2 u; } pk;
  pk.h[0] = __float2bfloat16((x2.x - mu) * rs * gg.x + bb.x);
  pk.h[1] = __float2bfloat16((x2.y - mu) * rs * gg.y + bb.y);
  pk.h[2] = __float2bfloat16((x2.z - mu) * rs * gg.z + bb.z);
  pk.h[3] = __float2bfloat16((x2.w - mu) * rs * gg.w + bb.w);
  reinterpret_cast<uint2*>(hb + (size_t)row * 1024)[tid] = pk.u;
}

// ------- GEMM, T3-minimal double-buffered (R9-proven 16x16x32 structure) -------
// VSPLIT: fused-QKV three-way epilogue (Q row-major, K/V fragment-linear).
// TP: blockIdx.z>0 tail blocks transpose W1/W2 (consumed 3 dispatches later);
// QKV GEMM is compute-bound so these HBM-bound blocks ride its memory slack.
template <int BM, int BN, int WM, int WN, int MINW,
          bool GELU, bool RES, bool OUTBF, bool VSPLIT, bool TP>
__global__ __launch_bounds__(WM * WN * 64, MINW) void gemm_db(
    const bf16* __restrict__ A, const bf16* __restrict__ BT,
    const float* __restrict__ bias, const float* __restrict__ res,
    float* __restrict__ outf, bf16* __restrict__ outb,
    bf16* __restrict__ kt, bf16* __restrict__ vt,
    const float* __restrict__ TW1, const float* __restrict__ TW2,
    bf16* __restrict__ TW1T, bf16* __restrict__ TW2T,
    int M, int N, int K) {
  constexpr int NW = WM * WN;
  constexpr int MT = BM / WM / 16, NT = BN / WN / 16;
  constexpr int ACH = BM / 8, BCH = BN / 8;
  constexpr int PW = (ACH + BCH) / NW;
  const int t = threadIdx.x;
  if constexpr (TP) {
    if (blockIdx.z > 0) {  // W1/W2 transpose tail: 2 tiles per 512-thread block
      __shared__ bf16 tt[2][32][33];
      int zi = blockIdx.z - 1;
      int g = t >> 8;
      int tile = (zi * 256 + blockIdx.y * 16 + blockIdx.x) * 2 + g;
      const float* src; bf16* dst; int K2, N2, tb;
      if (tile < 4096) { src = TW1; dst = TW1T; K2 = 1024; N2 = 4096; tb = tile; }
      else             { src = TW2; dst = TW2T; K2 = 4096; N2 = 1024; tb = tile - 4096; }
      int ntx = N2 >> 5;
      int bx = (tb % ntx) * 32, by = (tb / ntx) * 32;
      int tx = t & 31, ty = (t >> 5) & 7;
#pragma unroll
      for (int j = 0; j < 32; j += 8)
        tt[g][ty + j][tx] = __float2bfloat16(src[(size_t)(by + ty + j) * N2 + bx + tx]);
      __syncthreads();
#pragma unroll
      for (int j = 0; j < 32; j += 8)
        dst[(size_t)(bx + ty + j) * K2 + by + tx] = tt[g][tx][ty + j];
      return;
    }
  }
  __shared__ __align__(16) bf16 As[2][BM * 64];
  __shared__ __align__(16) bf16 Bs[2][BN * 64];
  const int lane = t & 63, w = t >> 6;
  const int wr = w / WN, wc = w % WN;
  const int l15 = lane & 15, l4 = lane >> 4;
  const int gx = gridDim.x, nwg = gx * gridDim.y;
  int bid = blockIdx.y * gx + blockIdx.x;
  int sbid = (bid & 7) * (nwg >> 3) + (bid >> 3);
  const int m0 = (sbid / gx) * BM, n0 = (sbid % gx) * BN;
  const int lr = lane >> 3;
  const int scol = ((lane & 7) * 8) ^ (lr * 8);

  auto stage = [&](int buf, int kt_) {
    const int k0 = kt_ << 6;
#pragma unroll
    for (int i = 0; i < PW; ++i) {
      int c = w * PW + i;
      if (c < ACH) {
        GLOAD_LDS16(A + (size_t)(m0 + c * 8 + lr) * K + k0 + scol, &As[buf][c * 512]);
      } else {
        int c2 = c - ACH;
        GLOAD_LDS16(BT + (size_t)(n0 + c2 * 8 + lr) * K + k0 + scol, &Bs[buf][c2 * 512]);
      }
    }
  };

  f32x4 acc[MT][NT] = {};
  const int nk = K >> 6;
  stage(0, 0);
  __syncthreads();
  int cur = 0;
  for (int kk = 0; kk < nk; ++kk) {
    if (kk + 1 < nk) stage(cur ^ 1, kk + 1);
#pragma unroll
    for (int ks = 0; ks < 2; ++ks) {
      bf16x8 af[MT], bfr[NT];
#pragma unroll
      for (int m = 0; m < MT; ++m)
        af[m] = *reinterpret_cast<const bf16x8*>(
            &As[cur][swz(wr * (BM / WM) + m * 16 + l15, ks * 32 + l4 * 8)]);
#pragma unroll
      for (int n = 0; n < NT; ++n)
        bfr[n] = *reinterpret_cast<const bf16x8*>(
            &Bs[cur][swz(wc * (BN / WN) + n * 16 + l15, ks * 32 + l4 * 8)]);
      __builtin_amdgcn_s_setprio(1);
#pragma unroll
      for (int m = 0; m < MT; ++m)
#pragma unroll
        for (int n = 0; n < NT; ++n)
          acc[m][n] = __builtin_amdgcn_mfma_f32_16x16x32_bf16(af[m], bfr[n], acc[m][n], 0, 0, 0);
      __builtin_amdgcn_s_setprio(0);
    }
    __syncthreads();
    cur ^= 1;
  }

#pragma unroll
  for (int m = 0; m < MT; ++m) {
    int gr0 = m0 + wr * (BM / WM) + m * 16 + l4 * 4;
#pragma unroll
    for (int n = 0; n < NT; ++n) {
      int gc = n0 + wc * (BN / WN) + n * 16 + l15;
      float bv = bias[gc];
#pragma unroll
      for (int q = 0; q < 4; ++q) {
        int gr = gr0 + q;
        float v = acc[m][n][q] + bv;
        if constexpr (GELU) v = 0.5f * v * (1.f + erff(v * 0.70710678118654752f));
        if constexpr (RES) v += res[(size_t)gr * N + gc];
        if constexpr (VSPLIT) {
          int s = gr & 1023, bb = gr >> 10;
          if (gc < 1024) {
            outb[(size_t)gr * N + gc] = __float2bfloat16(v);
          } else if (gc < 2048) {
            int hd = gc - 1024, hh = hd >> 6, d = hd & 63;
            int ln = (s & 15) | (((d >> 3) & 3) << 4);
            kt[(((size_t)(bb * 16 + hh) * 64 + (s >> 4)) << 10) + (d >> 5) * 512 +
               ln * 8 + (d & 7)] = __float2bfloat16(v);
          } else {
            int hd = gc - 2048, hh = hd >> 6, d = hd & 63;
            int ln = (d & 15) | (((s >> 3) & 3) << 4);
            vt[(((size_t)(bb * 16 + hh) * 4 + (d >> 4)) << 14) + ((s >> 5) << 9) +
               ln * 8 + (s & 7)] = __float2bfloat16(v);
          }
        } else if constexpr (OUTBF) {
          outb[(size_t)gr * N + gc] = __float2bfloat16(v);
        } else {
          outf[(size_t)gr * N + gc] = v;
        }
      }
    }
  }
}

// -------- flash attention: fragment-linear K/V, uniform-work pairs --------
__global__ __launch_bounds__(256, 2) void attn_kernel(
    const bf16* __restrict__ qkv, const bf16* __restrict__ kt,
    const bf16* __restrict__ vt, bf16* __restrict__ o) {
  const int S = 1024, QS = 3072, HD = 1024;
  const bf16* qg = qkv;
  int bid = blockIdx.x;                 // 0..511
  int xcd = bid & 7, j = bid >> 3;      // j 0..63
  int grp = xcd * 8 + (j >> 3);         // 0..63 = (b,h), 8 groups per XCD
  int pr = j & 7;                       // pair id 0..7
  const int b = grp >> 4, h = grp & 15;
  const int t = threadIdx.x, lane = t & 63, w = t >> 6;
  const int l15 = lane & 15, l4 = lane >> 4;

  constexpr int PSTR = 72;
  __shared__ __align__(16) bf16 P[4][16 * PSTR];

  const int bh = b * 16 + h;
  const bf16* kbase = kt + ((size_t)bh << 16) + lane * 8;
  const bf16* vbase = vt + ((size_t)bh << 16) + lane * 8;

  bf16x8 kA[8], kB[8];
  auto loadK = [&](int kb, bf16x8* kf) {
#pragma unroll
    for (int cb = 0; cb < 4; ++cb)
#pragma unroll
      for (int ks = 0; ks < 2; ++ks)
        kf[cb * 2 + ks] = *reinterpret_cast<const bf16x8*>(
            kbase + (((kb >> 4) + cb) << 10) + (ks << 9));
  };

  auto run_strip = [&](int q0) {
    bf16x8 qf0, qf1;
    {
      const bf16* qp = qg + (size_t)(b * S + q0 + l15) * QS + h * 64 + l4 * 8;
      qf0 = *reinterpret_cast<const bf16x8*>(qp);
      qf1 = *reinterpret_cast<const bf16x8*>(qp + 32);
    }
    f32x4 acc[4] = {};
    float mrow = -1e30f, lrow = 0.f;
    const int kmaxa = q0 + 15, kmax = kmaxa < 959 ? kmaxa : 959;
    const int nt = (kmax >> 6) + 1;
    loadK(0, kA);

    for (int kt_ = 0; kt_ < nt; ++kt_) {
      const int kb = kt_ << 6;
      bf16x8* kf = (kt_ & 1) ? kB : kA;
      bf16x8* kn = (kt_ & 1) ? kA : kB;
      bf16x8 vf[8];
#pragma unroll
      for (int n = 0; n < 4; ++n)
#pragma unroll
        for (int ks = 0; ks < 2; ++ks)
          vf[n * 2 + ks] = *reinterpret_cast<const bf16x8*>(
              vbase + (n << 14) + (((kb >> 5) + ks) << 9));
      if (kt_ + 1 < nt) loadK(kb + 64, kn);

      f32x4 sc[4];
      __builtin_amdgcn_s_setprio(1);
#pragma unroll
      for (int cb = 0; cb < 4; ++cb) {
        f32x4 z = {};
        z = __builtin_amdgcn_mfma_f32_16x16x32_bf16(kf[cb * 2 + 0], qf0, z, 0, 0, 0);
        z = __builtin_amdgcn_mfma_f32_16x16x32_bf16(kf[cb * 2 + 1], qf1, z, 0, 0, 0);
        sc[cb] = z;
      }
      __builtin_amdgcn_s_setprio(0);

      const int q = q0 + l15;
      float p[16];
#pragma unroll
      for (int cb = 0; cb < 4; ++cb)
#pragma unroll
        for (int r = 0; r < 4; ++r) {
          int kgl = kb + cb * 16 + l4 * 4 + r;
          p[cb * 4 + r] = (kgl > q) ? -1e30f : sc[cb][r] * 0.125f;
        }
      float tm = p[0];
#pragma unroll
      for (int i = 1; i < 16; ++i) tm = fmaxf(tm, p[i]);
      tm = fmaxf(tm, __shfl_xor(tm, 16));
      tm = fmaxf(tm, __shfl_xor(tm, 32));
      bool defer = __all(tm <= mrow + 8.f);   // T13
      float mn = defer ? mrow : fmaxf(mrow, tm);
      float ps = 0.f;
#pragma unroll
      for (int i = 0; i < 16; ++i) { p[i] = __expf(p[i] - mn); ps += p[i]; }
      ps += __shfl_xor(ps, 16);
      ps += __shfl_xor(ps, 32);
      if (defer) {
        lrow += ps;
      } else {
        float al = __expf(mrow - mn);
        mrow = mn;
        lrow = lrow * al + ps;
#pragma unroll
        for (int n = 0; n < 4; ++n)
#pragma unroll
          for (int r = 0; r < 4; ++r) acc[n][r] *= al;
      }
#pragma unroll
      for (int cb = 0; cb < 4; ++cb) {
        union { bf16 h4[4]; uint2 u; } pk;
#pragma unroll
        for (int r = 0; r < 4; ++r) pk.h4[r] = __float2bfloat16(p[cb * 4 + r]);
        *reinterpret_cast<uint2*>(&P[w][l15 * PSTR + cb * 16 + l4 * 4]) = pk.u;
      }
      asm volatile("" ::: "memory");
      bf16x8 pb0 = *reinterpret_cast<const bf16x8*>(&P[w][l15 * PSTR + l4 * 8]);
      bf16x8 pb1 = *reinterpret_cast<const bf16x8*>(&P[w][l15 * PSTR + 32 + l4 * 8]);
      __builtin_amdgcn_s_setprio(1);
#pragma unroll
      for (int n = 0; n < 4; ++n) {
        acc[n] = __builtin_amdgcn_mfma_f32_16x16x32_bf16(vf[n * 2 + 0], pb0, acc[n], 0, 0, 0);
        acc[n] = __builtin_amdgcn_mfma_f32_16x16x32_bf16(vf[n * 2 + 1], pb1, acc[n], 0, 0, 0);
      }
      __builtin_amdgcn_s_setprio(0);
    }

    float inv = 1.f / lrow;
#pragma unroll
    for (int n = 0; n < 4; ++n) {
      union { bf16 h4[4]; uint2 u; } pk;
#pragma unroll
      for (int r = 0; r < 4; ++r) pk.h4[r] = __float2bfloat16(acc[n][r] * inv);
      *reinterpret_cast<uint2*>(&P[w][l15 * PSTR + n * 16 + l4 * 4]) = pk.u;
    }
    asm volatile("" ::: "memory");
    {
      int qq = lane >> 2, c = lane & 3;
#pragma unroll
      for (int i = 0; i < 2; ++i) {
        uint4 ov = *reinterpret_cast<const uint4*>(&P[w][qq * PSTR + c * 16 + i * 8]);
        *reinterpret_cast<uint4*>(
            o + (size_t)(b * S + q0 + qq) * HD + h * 64 + c * 16 + i * 8) = ov;
      }
    }
    asm volatile("" ::: "memory");
  };

  run_strip(pr * 64 + w * 16);          // pr+1 tiles
  run_strip((15 - pr) * 64 + w * 16);   // 16-pr tiles -> 17 total, uniform
}

// ---------------- launch ----------------
extern "C" void kernel_launch(void* const* d_in, const int* in_sizes, int n_in,
                              void* d_out, int out_size, void* d_ws, size_t ws_size,
                              hipStream_t stream) {
  const float* input = (const float*)d_in[0];
  const float* ln1g = (const float*)d_in[3];
  const float* ln1b = (const float*)d_in[4];
  const float* ln2g = (const float*)d_in[5];
  const float* ln2b = (const float*)d_in[6];
  const float* ln3g = (const float*)d_in[7];
  const float* ln3b = (const float*)d_in[8];
  const float* Wq = (const float*)d_in[9];  const float* bq = (const float*)d_in[10];
  const float* Wk = (const float*)d_in[11]; const float* bk = (const float*)d_in[12];
  const float* Wv = (const float*)d_in[13]; const float* bv = (const float*)d_in[14];
  const float* Wo = (const float*)d_in[15]; const float* bo = (const float*)d_in[16];
  const float* W1 = (const float*)d_in[17]; const float* b1 = (const float*)d_in[18];
  const float* W2 = (const float*)d_in[19]; const float* b2 = (const float*)d_in[20];

  const int M = 4096, D = 1024, F = 4096;
  char* p = (char*)d_ws;
  size_t off = 0;
  auto nxt = [&](size_t n) { char* r = p + off; off += n; return r; };
  bf16* WqkvT = (bf16*)nxt((size_t)3 * D * D * 2);
  bf16* WoT = (bf16*)nxt((size_t)D * D * 2);
  bf16* W1T = (bf16*)nxt((size_t)F * D * 2);
  bf16* W2T = (bf16*)nxt((size_t)D * F * 2);
  float* bqkv = (float*)nxt(16384);
  float* xf  = (float*)nxt((size_t)M * D * 4);
  float* aof = (float*)nxt((size_t)M * D * 4);
  float* x2f = (float*)nxt((size_t)M * D * 4);
  bf16* xb = (bf16*)nxt((size_t)M * D * 2);
  bf16* qkv = (bf16*)nxt((size_t)M * 3 * D * 2);
  bf16* ktb = (bf16*)aof;                       // K packed, 8 MB (aof dead until Wo)
  bf16* vtb = (bf16*)((char*)aof + (size_t)8 * 1024 * 1024);  // V^T packed, 8 MB
  bf16* gb = (bf16*)xf;   // gelu out overlays xf+aof (both dead by then)
  bf16* ab = xb;
  bf16* hb = qkv;

  // prep: QKV/O transposes + bias concat + LN1
  prep_kernel<<<4108 + 4096, dim3(32, 8), 0, stream>>>(
      Wq, Wk, Wv, Wo, bq, bk, bv, WqkvT, WoT, bqkv,
      input, ln1g, ln1b, xf, xb);

  // fused QKV: [4096,3072], 256x192 dbuf tile, z=0: 256 gemm blocks;
  // z=1..16: 8192 W1/W2 transpose tiles riding the compute-bound dispatch.
  gemm_db<256, 192, 2, 4, 1, false, false, true, true, true>
      <<<dim3(16, 16, 17), 512, 0, stream>>>(
      xb, WqkvT, bqkv, nullptr, nullptr, qkv, ktb, vtb,
      W1, W2, W1T, W2T, M, 3 * D, D);

  attn_kernel<<<512, 256, 0, stream>>>(qkv, ktb, vtb, ab);

  gemm_db<128, 64, 2, 2, 4, false, false, false, false, false>
      <<<dim3(16, 32), 256, 0, stream>>>(
      ab, WoT, bo, nullptr, aof, nullptr, nullptr, nullptr,
      nullptr, nullptr, nullptr, nullptr, M, D, D);

  ln23_kernel<<<M, 256, 0, stream>>>(xf, aof, ln2g, ln2b, ln3g, ln3b, x2f, hb);

  // W1+GELU: [4096,4096], 2-phase 256^2 (R9-proven)
  gemm_db<256, 256, 2, 4, 2, true, false, true, false, false>
      <<<dim3(16, 16), 512, 0, stream>>>(
      hb, W1T, b1, nullptr, nullptr, gb, nullptr, nullptr,
      nullptr, nullptr, nullptr, nullptr, M, F, D);
  // W2+residual: [4096,1024], K=4096, 2-phase 128x64 (R9-proven)
  gemm_db<128, 64, 2, 2, 4, false, true, false, false, false>
      <<<dim3(16, 32), 256, 0, stream>>>(
      gb, W2T, b2, x2f, (float*)d_out, nullptr, nullptr, nullptr,
      nullptr, nullptr, nullptr, nullptr, M, D, F);
}

// Round 16
// 207.989 us; speedup vs baseline: 1.1945x; 1.0456x over previous
//
#include <hip/hip_runtime.h>
#include <hip/hip_bf16.h>

typedef __hip_bfloat16 bf16;
typedef __bf16 bf16x8 __attribute__((ext_vector_type(8)));
typedef float f32x4 __attribute__((ext_vector_type(4)));

#define DEV __device__ __forceinline__

DEV int swz(int r, int k) { return r * 64 + (k ^ ((r & 7) << 3)); }

#define GLOAD_LDS16(gaddr, laddr)                                              \
  __builtin_amdgcn_global_load_lds(                                            \
      (const __attribute__((address_space(1))) void*)(gaddr),                  \
      (__attribute__((address_space(3))) void*)(laddr), 16, 0, 0)

// ------ fused prep: 6 weight transposes + bias concat + LN1 ------
__global__ void prep_kernel(
    const float* __restrict__ Wq, const float* __restrict__ Wk,
    const float* __restrict__ Wv, const float* __restrict__ Wo,
    const float* __restrict__ W1, const float* __restrict__ W2,
    const float* __restrict__ bq, const float* __restrict__ bk,
    const float* __restrict__ bv,
    bf16* __restrict__ WqkvT, bf16* __restrict__ WoT,
    bf16* __restrict__ W1T, bf16* __restrict__ W2T, float* __restrict__ bqkv,
    const float* __restrict__ in, const float* __restrict__ g1,
    const float* __restrict__ b1v, float* __restrict__ xo, bf16* __restrict__ xb) {
  __shared__ bf16 t[32][33];
  __shared__ float ss[4], qq[4];
  int bid = blockIdx.x;
  if (bid >= 12300) {  // LN1 rows
    int row = bid - 12300, tid = threadIdx.y * 32 + threadIdx.x;
    int lane = tid & 63, w = tid >> 6;
    float4 v = reinterpret_cast<const float4*>(in + (size_t)row * 1024)[tid];
    float s = v.x + v.y + v.z + v.w;
    float sq = v.x * v.x + v.y * v.y + v.z * v.z + v.w * v.w;
#pragma unroll
    for (int m = 32; m; m >>= 1) { s += __shfl_xor(s, m); sq += __shfl_xor(sq, m); }
    if (lane == 0) { ss[w] = s; qq[w] = sq; }
    __syncthreads();
    s = ss[0] + ss[1] + ss[2] + ss[3];
    sq = qq[0] + qq[1] + qq[2] + qq[3];
    float mu = s * (1.f / 1024.f);
    float rs = rsqrtf(sq * (1.f / 1024.f) - mu * mu + 1e-5f);
    float4 gg = reinterpret_cast<const float4*>(g1)[tid];
    float4 bb = reinterpret_cast<const float4*>(b1v)[tid];
    float4 y;
    y.x = (v.x - mu) * rs * gg.x + bb.x;
    y.y = (v.y - mu) * rs * gg.y + bb.y;
    y.z = (v.z - mu) * rs * gg.z + bb.z;
    y.w = (v.w - mu) * rs * gg.w + bb.w;
    reinterpret_cast<float4*>(xo + (size_t)row * 1024)[tid] = y;
    union { bf16 h[4]; uint2 u; } pk;
    pk.h[0] = __float2bfloat16(y.x); pk.h[1] = __float2bfloat16(y.y);
    pk.h[2] = __float2bfloat16(y.z); pk.h[3] = __float2bfloat16(y.w);
    reinterpret_cast<uint2*>(xb + (size_t)row * 1024)[tid] = pk.u;
    return;
  }
  if (bid >= 12288) {  // bias concat
    int i = (bid - 12288) * 256 + threadIdx.y * 32 + threadIdx.x;
    if (i < 3072)
      bqkv[i] = i < 1024 ? bq[i] : (i < 2048 ? bk[i - 1024] : bv[i - 2048]);
    return;
  }
  const float* src; bf16* dst; int K, N, tb;
  if (bid < 4096) {
    int wsel = bid >> 10;
    src = wsel == 0 ? Wq : wsel == 1 ? Wk : wsel == 2 ? Wv : Wo;
    dst = wsel < 3 ? WqkvT + (size_t)wsel * 1048576 : WoT;
    K = 1024; N = 1024; tb = bid & 1023;
  } else if (bid < 8192) {
    src = W1; dst = W1T; K = 1024; N = 4096; tb = bid - 4096;
  } else {
    src = W2; dst = W2T; K = 4096; N = 1024; tb = bid - 8192;
  }
  int ntx = N >> 5;
  int bx = (tb % ntx) * 32, by = (tb / ntx) * 32;
  int tx = threadIdx.x, ty = threadIdx.y;
#pragma unroll
  for (int j = 0; j < 32; j += 8)
    t[ty + j][tx] = __float2bfloat16(src[(size_t)(by + ty + j) * N + bx + tx]);
  __syncthreads();
#pragma unroll
  for (int j = 0; j < 32; j += 8)
    dst[(size_t)(bx + ty + j) * K + by + tx] = t[tx][ty + j];
}

// ------- LN23: x2 = x + LN2(ao[bf16]); h = LN3(x2) -------
__global__ __launch_bounds__(256) void ln23_kernel(
    const float* __restrict__ x, const bf16* __restrict__ ao,
    const float* __restrict__ g2, const float* __restrict__ b2,
    const float* __restrict__ g3, const float* __restrict__ b3,
    float* __restrict__ x2o, bf16* __restrict__ hb) {
  int row = blockIdx.x, tid = threadIdx.x;
  int lane = tid & 63, w = tid >> 6;
  union { uint2 u; bf16 h[4]; } av;
  av.u = reinterpret_cast<const uint2*>(ao + (size_t)row * 1024)[tid];
  float a0 = __bfloat162float(av.h[0]), a1 = __bfloat162float(av.h[1]);
  float a2 = __bfloat162float(av.h[2]), a3 = __bfloat162float(av.h[3]);
  float s = a0 + a1 + a2 + a3;
  float sq = a0 * a0 + a1 * a1 + a2 * a2 + a3 * a3;
#pragma unroll
  for (int m = 32; m; m >>= 1) { s += __shfl_xor(s, m); sq += __shfl_xor(sq, m); }
  __shared__ float s1[4], q1[4], s2[4], q2[4];
  if (lane == 0) { s1[w] = s; q1[w] = sq; }
  __syncthreads();
  s = s1[0] + s1[1] + s1[2] + s1[3];
  sq = q1[0] + q1[1] + q1[2] + q1[3];
  float mu = s * (1.f / 1024.f);
  float rs = rsqrtf(sq * (1.f / 1024.f) - mu * mu + 1e-5f);
  float4 xr = reinterpret_cast<const float4*>(x + (size_t)row * 1024)[tid];
  float4 gg = reinterpret_cast<const float4*>(g2)[tid];
  float4 bb = reinterpret_cast<const float4*>(b2)[tid];
  float4 x2;
  x2.x = xr.x + (a0 - mu) * rs * gg.x + bb.x;
  x2.y = xr.y + (a1 - mu) * rs * gg.y + bb.y;
  x2.z = xr.z + (a2 - mu) * rs * gg.z + bb.z;
  x2.w = xr.w + (a3 - mu) * rs * gg.w + bb.w;
  reinterpret_cast<float4*>(x2o + (size_t)row * 1024)[tid] = x2;
  s = x2.x + x2.y + x2.z + x2.w;
  sq = x2.x * x2.x + x2.y * x2.y + x2.z * x2.z + x2.w * x2.w;
#pragma unroll
  for (int m = 32; m; m >>= 1) { s += __shfl_xor(s, m); sq += __shfl_xor(sq, m); }
  if (lane == 0) { s2[w] = s; q2[w] = sq; }
  __syncthreads();
  s = s2[0] + s2[1] + s2[2] + s2[3];
  sq = q2[0] + q2[1] + q2[2] + q2[3];
  mu = s * (1.f / 1024.f);
  rs = rsqrtf(sq * (1.f / 1024.f) - mu * mu + 1e-5f);
  gg = reinterpret_cast<const float4*>(g3)[tid];
  bb = reinterpret_cast<const float4*>(b3)[tid];
  union { bf16 h[4]; uint2 u; } pk;
  pk.h[0] = __float2bfloat16((x2.x - mu) * rs * gg.x + bb.x);
  pk.h[1] = __float2bfloat16((x2.y - mu) * rs * gg.y + bb.y);
  pk.h[2] = __float2bfloat16((x2.z - mu) * rs * gg.z + bb.z);
  pk.h[3] = __float2bfloat16((x2.w - mu) * rs * gg.w + bb.w);
  reinterpret_cast<uint2*>(hb + (size_t)row * 1024)[tid] = pk.u;
}

// ------- GEMM, T3-minimal double-buffered (R9-proven); VSPLIT for fused QKV -------
template <int BM, int BN, int WM, int WN, int MINW,
          bool GELU, bool RES, bool OUTBF, bool VSPLIT>
__global__ __launch_bounds__(WM * WN * 64, MINW) void gemm_db(
    const bf16* __restrict__ A, const bf16* __restrict__ BT,
    const float* __restrict__ bias, const float* __restrict__ res,
    float* __restrict__ outf, bf16* __restrict__ outb,
    bf16* __restrict__ kt, bf16* __restrict__ vt,
    int M, int N, int K) {
  constexpr int NW = WM * WN;
  constexpr int MT = BM / WM / 16, NT = BN / WN / 16;
  constexpr int ACH = BM / 8, BCH = BN / 8;
  constexpr int PW = (ACH + BCH) / NW;
  __shared__ __align__(16) bf16 As[2][BM * 64];
  __shared__ __align__(16) bf16 Bs[2][BN * 64];
  const int t = threadIdx.x, lane = t & 63, w = t >> 6;
  const int wr = w / WN, wc = w % WN;
  const int l15 = lane & 15, l4 = lane >> 4;
  const int gx = gridDim.x, nwg = gx * gridDim.y;
  int bid = blockIdx.y * gx + blockIdx.x;
  int sbid = (bid & 7) * (nwg >> 3) + (bid >> 3);
  const int m0 = (sbid / gx) * BM, n0 = (sbid % gx) * BN;
  const int lr = lane >> 3;
  const int scol = ((lane & 7) * 8) ^ (lr * 8);

  auto stage = [&](int buf, int kt_) {
    const int k0 = kt_ << 6;
#pragma unroll
    for (int i = 0; i < PW; ++i) {
      int c = w * PW + i;
      if (c < ACH) {
        GLOAD_LDS16(A + (size_t)(m0 + c * 8 + lr) * K + k0 + scol, &As[buf][c * 512]);
      } else {
        int c2 = c - ACH;
        GLOAD_LDS16(BT + (size_t)(n0 + c2 * 8 + lr) * K + k0 + scol, &Bs[buf][c2 * 512]);
      }
    }
  };

  f32x4 acc[MT][NT] = {};
  const int nk = K >> 6;
  stage(0, 0);
  __syncthreads();
  int cur = 0;
  for (int kk = 0; kk < nk; ++kk) {
    if (kk + 1 < nk) stage(cur ^ 1, kk + 1);
#pragma unroll
    for (int ks = 0; ks < 2; ++ks) {
      bf16x8 af[MT], bfr[NT];
#pragma unroll
      for (int m = 0; m < MT; ++m)
        af[m] = *reinterpret_cast<const bf16x8*>(
            &As[cur][swz(wr * (BM / WM) + m * 16 + l15, ks * 32 + l4 * 8)]);
#pragma unroll
      for (int n = 0; n < NT; ++n)
        bfr[n] = *reinterpret_cast<const bf16x8*>(
            &Bs[cur][swz(wc * (BN / WN) + n * 16 + l15, ks * 32 + l4 * 8)]);
      __builtin_amdgcn_s_setprio(1);
#pragma unroll
      for (int m = 0; m < MT; ++m)
#pragma unroll
        for (int n = 0; n < NT; ++n)
          acc[m][n] = __builtin_amdgcn_mfma_f32_16x16x32_bf16(af[m], bfr[n], acc[m][n], 0, 0, 0);
      __builtin_amdgcn_s_setprio(0);
    }
    __syncthreads();
    cur ^= 1;
  }

#pragma unroll
  for (int m = 0; m < MT; ++m) {
    int gr0 = m0 + wr * (BM / WM) + m * 16 + l4 * 4;
#pragma unroll
    for (int n = 0; n < NT; ++n) {
      int gc = n0 + wc * (BN / WN) + n * 16 + l15;
      float bv = bias[gc];
#pragma unroll
      for (int q = 0; q < 4; ++q) {
        int gr = gr0 + q;
        float v = acc[m][n][q] + bv;
        if constexpr (GELU) v = 0.5f * v * (1.f + erff(v * 0.70710678118654752f));
        if constexpr (RES) v += res[(size_t)gr * N + gc];
        if constexpr (VSPLIT) {
          int s = gr & 1023, bb = gr >> 10;
          if (gc < 1024) {
            outb[(size_t)gr * N + gc] = __float2bfloat16(v);
          } else if (gc < 2048) {
            int hd = gc - 1024, hh = hd >> 6, d = hd & 63;
            int ln = (s & 15) | (((d >> 3) & 3) << 4);
            kt[(((size_t)(bb * 16 + hh) * 64 + (s >> 4)) << 10) + (d >> 5) * 512 +
               ln * 8 + (d & 7)] = __float2bfloat16(v);
          } else {
            int hd = gc - 2048, hh = hd >> 6, d = hd & 63;
            int ln = (d & 15) | (((s >> 3) & 3) << 4);
            vt[(((size_t)(bb * 16 + hh) * 4 + (d >> 4)) << 14) + ((s >> 5) << 9) +
               ln * 8 + (s & 7)] = __float2bfloat16(v);
          }
        } else if constexpr (OUTBF) {
          outb[(size_t)gr * N + gc] = __float2bfloat16(v);
        } else {
          outf[(size_t)gr * N + gc] = v;
        }
      }
    }
  }
}

// -------- flash attention: fragment-linear K/V, uniform-work pairs --------
__global__ __launch_bounds__(256, 2) void attn_kernel(
    const bf16* __restrict__ qkv, const bf16* __restrict__ kt,
    const bf16* __restrict__ vt, bf16* __restrict__ o) {
  const int S = 1024, QS = 3072, HD = 1024;
  const bf16* qg = qkv;
  int bid = blockIdx.x;                 // 0..511
  int xcd = bid & 7, j = bid >> 3;      // j 0..63
  int grp = xcd * 8 + (j >> 3);         // 0..63 = (b,h), 8 groups per XCD
  int pr = j & 7;                       // pair id 0..7
  const int b = grp >> 4, h = grp & 15;
  const int t = threadIdx.x, lane = t & 63, w = t >> 6;
  const int l15 = lane & 15, l4 = lane >> 4;

  constexpr int PSTR = 72;
  __shared__ __align__(16) bf16 P[4][16 * PSTR];

  const int bh = b * 16 + h;
  const bf16* kbase = kt + ((size_t)bh << 16) + lane * 8;
  const bf16* vbase = vt + ((size_t)bh << 16) + lane * 8;

  bf16x8 kA[8], kB[8];
  auto loadK = [&](int kb, bf16x8* kf) {
#pragma unroll
    for (int cb = 0; cb < 4; ++cb)
#pragma unroll
      for (int ks = 0; ks < 2; ++ks)
        kf[cb * 2 + ks] = *reinterpret_cast<const bf16x8*>(
            kbase + (((kb >> 4) + cb) << 10) + (ks << 9));
  };

  auto run_strip = [&](int q0) {
    bf16x8 qf0, qf1;
    {
      const bf16* qp = qg + (size_t)(b * S + q0 + l15) * QS + h * 64 + l4 * 8;
      qf0 = *reinterpret_cast<const bf16x8*>(qp);
      qf1 = *reinterpret_cast<const bf16x8*>(qp + 32);
    }
    f32x4 acc[4] = {};
    float mrow = -1e30f, lrow = 0.f;
    const int kmaxa = q0 + 15, kmax = kmaxa < 959 ? kmaxa : 959;
    const int nt = (kmax >> 6) + 1;
    loadK(0, kA);

    for (int kt_ = 0; kt_ < nt; ++kt_) {
      const int kb = kt_ << 6;
      bf16x8* kf = (kt_ & 1) ? kB : kA;
      bf16x8* kn = (kt_ & 1) ? kA : kB;
      bf16x8 vf[8];
#pragma unroll
      for (int n = 0; n < 4; ++n)
#pragma unroll
        for (int ks = 0; ks < 2; ++ks)
          vf[n * 2 + ks] = *reinterpret_cast<const bf16x8*>(
              vbase + (n << 14) + (((kb >> 5) + ks) << 9));
      if (kt_ + 1 < nt) loadK(kb + 64, kn);

      f32x4 sc[4];
      __builtin_amdgcn_s_setprio(1);
#pragma unroll
      for (int cb = 0; cb < 4; ++cb) {
        f32x4 z = {};
        z = __builtin_amdgcn_mfma_f32_16x16x32_bf16(kf[cb * 2 + 0], qf0, z, 0, 0, 0);
        z = __builtin_amdgcn_mfma_f32_16x16x32_bf16(kf[cb * 2 + 1], qf1, z, 0, 0, 0);
        sc[cb] = z;
      }
      __builtin_amdgcn_s_setprio(0);

      const int q = q0 + l15;
      float p[16];
#pragma unroll
      for (int cb = 0; cb < 4; ++cb)
#pragma unroll
        for (int r = 0; r < 4; ++r) {
          int kgl = kb + cb * 16 + l4 * 4 + r;
          p[cb * 4 + r] = (kgl > q) ? -1e30f : sc[cb][r] * 0.125f;
        }
      float tm = p[0];
#pragma unroll
      for (int i = 1; i < 16; ++i) tm = fmaxf(tm, p[i]);
      tm = fmaxf(tm, __shfl_xor(tm, 16));
      tm = fmaxf(tm, __shfl_xor(tm, 32));
      bool defer = __all(tm <= mrow + 8.f);   // T13
      float mn = defer ? mrow : fmaxf(mrow, tm);
      float ps = 0.f;
#pragma unroll
      for (int i = 0; i < 16; ++i) { p[i] = __expf(p[i] - mn); ps += p[i]; }
      ps += __shfl_xor(ps, 16);
      ps += __shfl_xor(ps, 32);
      if (defer) {
        lrow += ps;
      } else {
        float al = __expf(mrow - mn);
        mrow = mn;
        lrow = lrow * al + ps;
#pragma unroll
        for (int n = 0; n < 4; ++n)
#pragma unroll
          for (int r = 0; r < 4; ++r) acc[n][r] *= al;
      }
#pragma unroll
      for (int cb = 0; cb < 4; ++cb) {
        union { bf16 h4[4]; uint2 u; } pk;
#pragma unroll
        for (int r = 0; r < 4; ++r) pk.h4[r] = __float2bfloat16(p[cb * 4 + r]);
        *reinterpret_cast<uint2*>(&P[w][l15 * PSTR + cb * 16 + l4 * 4]) = pk.u;
      }
      asm volatile("" ::: "memory");
      bf16x8 pb0 = *reinterpret_cast<const bf16x8*>(&P[w][l15 * PSTR + l4 * 8]);
      bf16x8 pb1 = *reinterpret_cast<const bf16x8*>(&P[w][l15 * PSTR + 32 + l4 * 8]);
      __builtin_amdgcn_s_setprio(1);
#pragma unroll
      for (int n = 0; n < 4; ++n) {
        acc[n] = __builtin_amdgcn_mfma_f32_16x16x32_bf16(vf[n * 2 + 0], pb0, acc[n], 0, 0, 0);
        acc[n] = __builtin_amdgcn_mfma_f32_16x16x32_bf16(vf[n * 2 + 1], pb1, acc[n], 0, 0, 0);
      }
      __builtin_amdgcn_s_setprio(0);
    }

    float inv = 1.f / lrow;
#pragma unroll
    for (int n = 0; n < 4; ++n) {
      union { bf16 h4[4]; uint2 u; } pk;
#pragma unroll
      for (int r = 0; r < 4; ++r) pk.h4[r] = __float2bfloat16(acc[n][r] * inv);
      *reinterpret_cast<uint2*>(&P[w][l15 * PSTR + n * 16 + l4 * 4]) = pk.u;
    }
    asm volatile("" ::: "memory");
    {
      int qq = lane >> 2, c = lane & 3;
#pragma unroll
      for (int i = 0; i < 2; ++i) {
        uint4 ov = *reinterpret_cast<const uint4*>(&P[w][qq * PSTR + c * 16 + i * 8]);
        *reinterpret_cast<uint4*>(
            o + (size_t)(b * S + q0 + qq) * HD + h * 64 + c * 16 + i * 8) = ov;
      }
    }
    asm volatile("" ::: "memory");
  };

  run_strip(pr * 64 + w * 16);          // pr+1 tiles
  run_strip((15 - pr) * 64 + w * 16);   // 16-pr tiles -> 17 total, uniform
}

// ---------------- launch ----------------
extern "C" void kernel_launch(void* const* d_in, const int* in_sizes, int n_in,
                              void* d_out, int out_size, void* d_ws, size_t ws_size,
                              hipStream_t stream) {
  const float* input = (const float*)d_in[0];
  const float* ln1g = (const float*)d_in[3];
  const float* ln1b = (const float*)d_in[4];
  const float* ln2g = (const float*)d_in[5];
  const float* ln2b = (const float*)d_in[6];
  const float* ln3g = (const float*)d_in[7];
  const float* ln3b = (const float*)d_in[8];
  const float* Wq = (const float*)d_in[9];  const float* bq = (const float*)d_in[10];
  const float* Wk = (const float*)d_in[11]; const float* bk = (const float*)d_in[12];
  const float* Wv = (const float*)d_in[13]; const float* bv = (const float*)d_in[14];
  const float* Wo = (const float*)d_in[15]; const float* bo = (const float*)d_in[16];
  const float* W1 = (const float*)d_in[17]; const float* b1 = (const float*)d_in[18];
  const float* W2 = (const float*)d_in[19]; const float* b2 = (const float*)d_in[20];

  const int M = 4096, D = 1024, F = 4096;
  char* p = (char*)d_ws;
  size_t off = 0;
  auto nxt = [&](size_t n) { char* r = p + off; off += n; return r; };
  bf16* WqkvT = (bf16*)nxt((size_t)3 * D * D * 2);
  bf16* WoT = (bf16*)nxt((size_t)D * D * 2);
  bf16* W1T = (bf16*)nxt((size_t)F * D * 2);
  bf16* W2T = (bf16*)nxt((size_t)D * F * 2);
  float* bqkv = (float*)nxt(16384);
  float* xf  = (float*)nxt((size_t)M * D * 4);
  float* aof = (float*)nxt((size_t)M * D * 4);   // region reused: ktb/vtb then aob
  float* x2f = (float*)nxt((size_t)M * D * 4);
  bf16* xb = (bf16*)nxt((size_t)M * D * 2);
  bf16* qkv = (bf16*)nxt((size_t)M * 3 * D * 2);
  bf16* ktb = (bf16*)aof;                       // K packed, 8 MB (dead after attn)
  bf16* vtb = (bf16*)((char*)aof + (size_t)8 * 1024 * 1024);  // V^T packed, 8 MB
  bf16* aob = (bf16*)aof;                       // Wo out bf16, 8 MB (after attn)
  bf16* gb = (bf16*)xf;   // gelu out 32MB overlays xf+aof (both dead by then)
  bf16* ab = xb;
  bf16* hb = qkv;

  // prep: all 6 weight transposes + bias concat + LN1 (one launch)
  prep_kernel<<<12300 + 4096, dim3(32, 8), 0, stream>>>(
      Wq, Wk, Wv, Wo, W1, W2, bq, bk, bv, WqkvT, WoT, W1T, W2T, bqkv,
      input, ln1g, ln1b, xf, xb);

  // fused QKV: [4096,3072], 256x192 dbuf tile, 256 blocks (full CU cover)
  gemm_db<256, 192, 2, 4, 1, false, false, true, true>
      <<<dim3(16, 16), 512, 0, stream>>>(
      xb, WqkvT, bqkv, nullptr, nullptr, qkv, ktb, vtb, M, 3 * D, D);

  attn_kernel<<<512, 256, 0, stream>>>(qkv, ktb, vtb, ab);

  // Wo: bf16 output (feeds LN2 only; halves aof traffic)
  gemm_db<128, 64, 2, 2, 4, false, false, true, false>
      <<<dim3(16, 32), 256, 0, stream>>>(
      ab, WoT, bo, nullptr, nullptr, aob, nullptr, nullptr, M, D, D);

  ln23_kernel<<<M, 256, 0, stream>>>(xf, aob, ln2g, ln2b, ln3g, ln3b, x2f, hb);

  // W1+GELU: [4096,4096], 2-phase 256^2 (R9-proven)
  gemm_db<256, 256, 2, 4, 2, true, false, true, false>
      <<<dim3(16, 16), 512, 0, stream>>>(
      hb, W1T, b1, nullptr, nullptr, gb, nullptr, nullptr, M, F, D);
  // W2+residual: [4096,1024], K=4096, 2-phase 128x64 (R9-proven)
  gemm_db<128, 64, 2, 2, 4, false, true, false, false>
      <<<dim3(16, 32), 256, 0, stream>>>(
      gb, W2T, b2, x2f, (float*)d_out, nullptr, nullptr, nullptr, M, D, F);
}